// Round 1
// baseline (12631.285 us; speedup 1.0000x reference)
//
#include <hip/hip_runtime.h>

#define N_NODES 100000
#define N_EDGES 3200000

struct alignas(16) F4 { float v[4]; };
struct alignas(8)  F2 { float v[2]; };

// ---------------- utility ----------------
__global__ __launch_bounds__(256) void k_zero2(int* __restrict__ a, int* __restrict__ b, int n) {
    int i = blockIdx.x * 256 + threadIdx.x;
    if (i < n) { a[i] = 0; b[i] = 0; }
}

// ---------------- CSR build ----------------
__global__ __launch_bounds__(256) void k_hist(const int* __restrict__ rows, int* __restrict__ cnt) {
    int e = blockIdx.x * 256 + threadIdx.x;   // grid is exactly E/256
    atomicAdd(&cnt[rows[e]], 1);
}

__global__ __launch_bounds__(256) void k_blocksum(const int* __restrict__ cnt, int* __restrict__ bsum, int n) {
    __shared__ int red[256];
    int b = blockIdx.x, t = threadIdx.x;
    int base = b * 1024 + t * 4;
    int s = 0;
#pragma unroll
    for (int j = 0; j < 4; ++j) { int idx = base + j; if (idx < n) s += cnt[idx]; }
    red[t] = s; __syncthreads();
    for (int off = 128; off > 0; off >>= 1) {
        if (t < off) red[t] += red[t + off];
        __syncthreads();
    }
    if (t == 0) bsum[b] = red[0];
}

__global__ __launch_bounds__(128) void k_scan_small(int* __restrict__ b, int n) {
    // one block of 128 threads; n <= 128; exclusive scan in-place
    __shared__ int s[128];
    int t = threadIdx.x;
    int v = (t < n) ? b[t] : 0;
    s[t] = v; __syncthreads();
    for (int off = 1; off < 128; off <<= 1) {
        int x = (t >= off) ? s[t - off] : 0;
        __syncthreads();
        s[t] += x;
        __syncthreads();
    }
    if (t < n) b[t] = s[t] - v;
}

__global__ __launch_bounds__(256) void k_scan_block(const int* __restrict__ cnt, const int* __restrict__ bsum,
                                                    int* __restrict__ ptr, int n, int total) {
    __shared__ int ts[256];
    int b = blockIdx.x, t = threadIdx.x;
    int base = b * 1024 + t * 4;
    int v[4]; int s = 0;
#pragma unroll
    for (int j = 0; j < 4; ++j) { v[j] = (base + j < n) ? cnt[base + j] : 0; s += v[j]; }
    ts[t] = s; __syncthreads();
    for (int off = 1; off < 256; off <<= 1) {
        int x = (t >= off) ? ts[t - off] : 0;
        __syncthreads();
        ts[t] += x;
        __syncthreads();
    }
    int run = bsum[b] + ts[t] - s;   // exclusive prefix for this thread's 4 elements
#pragma unroll
    for (int j = 0; j < 4; ++j) { if (base + j < n) ptr[base + j] = run; run += v[j]; }
    if (b == 0 && t == 0) ptr[n] = total;
}

__global__ __launch_bounds__(256) void k_scatter(const int* __restrict__ rows, const int* __restrict__ cols,
                                                  const float* __restrict__ vals, const int* __restrict__ ptr,
                                                  int* __restrict__ fill, int* __restrict__ scols,
                                                  float* __restrict__ svals) {
    int e = blockIdx.x * 256 + threadIdx.x;   // grid is exactly E/256
    int r = rows[e];
    int p = ptr[r] + atomicAdd(&fill[r], 1);
    scols[p] = cols[e];
    svals[p] = vals[e];
}

// ---------------- SpMM (CSR, wave per row, fused bias+ReLU) ----------------
template<int D>
__global__ __launch_bounds__(256) void k_spmm(const int* __restrict__ ptr, const int* __restrict__ scols,
                                              const float* __restrict__ svals, const float* __restrict__ dense,
                                              const float* __restrict__ bias, float* __restrict__ outp) {
    constexpr int V = D / 64;                    // floats per lane (4 for D=256, 2 for D=128)
    int lane = threadIdx.x & 63;
    int row  = blockIdx.x * 4 + (threadIdx.x >> 6);   // grid*4 == N exactly
    float acc[V];
#pragma unroll
    for (int j = 0; j < V; ++j) acc[j] = 0.f;
    int s = ptr[row], e = ptr[row + 1];
    const float* __restrict__ dbase = dense + lane * V;
    int i = s;
    for (; i + 2 <= e; i += 2) {                 // 2-edge unroll: two independent gather chains
        int   c0 = scols[i],  c1 = scols[i + 1];
        float v0 = svals[i],  v1 = svals[i + 1];
        const float* p0 = dbase + (size_t)c0 * D;
        const float* p1 = dbase + (size_t)c1 * D;
        if constexpr (V == 4) {
            F4 a0 = *(const F4*)p0, a1 = *(const F4*)p1;
#pragma unroll
            for (int j = 0; j < 4; ++j) acc[j] += v0 * a0.v[j] + v1 * a1.v[j];
        } else {
            F2 a0 = *(const F2*)p0, a1 = *(const F2*)p1;
#pragma unroll
            for (int j = 0; j < 2; ++j) acc[j] += v0 * a0.v[j] + v1 * a1.v[j];
        }
    }
    if (i < e) {
        int c0 = scols[i]; float v0 = svals[i];
        const float* p0 = dbase + (size_t)c0 * D;
        if constexpr (V == 4) {
            F4 a0 = *(const F4*)p0;
#pragma unroll
            for (int j = 0; j < 4; ++j) acc[j] += v0 * a0.v[j];
        } else {
            F2 a0 = *(const F2*)p0;
#pragma unroll
            for (int j = 0; j < 2; ++j) acc[j] += v0 * a0.v[j];
        }
    }
    // epilogue: +bias, ReLU (all 3 uses in this net are consumed through ReLU)
    const float* bp = bias + lane * V;
    float* op = outp + (size_t)row * D + lane * V;
    if constexpr (V == 4) {
        F4 o;
#pragma unroll
        for (int j = 0; j < 4; ++j) { float t = acc[j] + bp[j]; o.v[j] = t > 0.f ? t : 0.f; }
        *(F4*)op = o;
    } else {
        F2 o;
#pragma unroll
        for (int j = 0; j < 2; ++j) { float t = acc[j] + bp[j]; o.v[j] = t > 0.f ? t : 0.f; }
        *(F2*)op = o;
    }
}

// ---------------- fp32 GEMM: [N,K] @ [K,M] -> [N,M], tile 64 x M ----------------
template<int K, int M>
__global__ __launch_bounds__(256) void k_gemm(const float* __restrict__ X, const float* __restrict__ W,
                                              float* __restrict__ Y) {
    constexpr int CG  = M / 4;         // col groups of 4
    constexpr int TYN = 256 / CG;      // row-group count (M=256 -> 4, M=128 -> 8)
    constexpr int RPT = 64 / TYN;      // rows per thread (16 or 8)
    __shared__ float xs[64][36];       // 32-wide K chunk, padded to 36 (144B rows, 16B aligned)
    int tid = threadIdx.x;
    int tx = tid % CG, ty = tid / CG;
    int r0 = blockIdx.x * 64;
    float acc[RPT][4];
#pragma unroll
    for (int r = 0; r < RPT; ++r)
#pragma unroll
        for (int c = 0; c < 4; ++c) acc[r][c] = 0.f;

    for (int k0 = 0; k0 < K; k0 += 32) {
        __syncthreads();
        // stage x tile: 64 rows x 32 floats = 512 float4, 2 per thread, coalesced
#pragma unroll
        for (int i = 0; i < 2; ++i) {
            int f  = tid + i * 256;
            int rr = f >> 3;
            int c4 = f & 7;
            int grow = r0 + rr;
            F4 val = {0.f, 0.f, 0.f, 0.f};
            if (grow < N_NODES) val = *(const F4*)&X[(size_t)grow * K + k0 + c4 * 4];
            *(F4*)&xs[rr][c4 * 4] = val;
        }
        __syncthreads();
#pragma unroll
        for (int kb = 0; kb < 8; ++kb) {
            const float* wp = &W[(size_t)(k0 + kb * 4) * M + tx * 4];   // L2-hot (W <= 512KB)
            F4 w0 = *(const F4*)(wp);
            F4 w1 = *(const F4*)(wp + M);
            F4 w2 = *(const F4*)(wp + 2 * M);
            F4 w3 = *(const F4*)(wp + 3 * M);
#pragma unroll
            for (int r = 0; r < RPT; ++r) {
                F4 xv = *(const F4*)&xs[ty * RPT + r][kb * 4];   // wave-uniform -> LDS broadcast
#pragma unroll
                for (int c = 0; c < 4; ++c)
                    acc[r][c] += xv.v[0] * w0.v[c] + xv.v[1] * w1.v[c]
                               + xv.v[2] * w2.v[c] + xv.v[3] * w3.v[c];
            }
        }
    }
#pragma unroll
    for (int r = 0; r < RPT; ++r) {
        int grow = r0 + ty * RPT + r;
        if (grow < N_NODES) {
            F4 o;
#pragma unroll
            for (int c = 0; c < 4; ++c) o.v[c] = acc[r][c];
            *(F4*)&Y[(size_t)grow * M + tx * 4] = o;
        }
    }
}

// ---------------- final dense: [N,128] @ [128,16] + bd ----------------
__global__ __launch_bounds__(256) void k_gemm4(const float* __restrict__ X, const float* __restrict__ Wd,
                                               const float* __restrict__ bd, float* __restrict__ out) {
    __shared__ float xs[16][132];      // pad 128 -> 132 to break 4-way bank conflict
    __shared__ float ws[128 * 16];
    __shared__ float bs[16];
    int tid = threadIdx.x;
    int r0 = blockIdx.x * 16;          // N % 16 == 0
#pragma unroll
    for (int i = 0; i < 2; ++i) {      // stage Wd: 2048 floats
        int f = tid + i * 256;
        *(F4*)&ws[f * 4] = *(const F4*)&Wd[f * 4];
    }
    if (tid < 16) bs[tid] = bd[tid];
#pragma unroll
    for (int i = 0; i < 2; ++i) {      // stage x tile: 16 rows x 128
        int f  = tid + i * 256;
        int rr = f >> 5;
        int c4 = f & 31;
        *(F4*)&xs[rr][c4 * 4] = *(const F4*)&X[(size_t)(r0 + rr) * 128 + c4 * 4];
    }
    __syncthreads();
    int c = tid & 15, r = tid >> 4;
    float acc = bs[c];
#pragma unroll
    for (int k = 0; k < 128; ++k) acc += xs[r][k] * ws[k * 16 + c];
    out[(size_t)(r0 + r) * 16 + c] = acc;
}

// ---------------- host ----------------
extern "C" void kernel_launch(void* const* d_in, const int* in_sizes, int n_in,
                              void* d_out, int out_size, void* d_ws, size_t ws_size,
                              hipStream_t stream) {
    const int N = N_NODES, E = N_EDGES;
    const float* x  = (const float*)d_in[0];
    // branch order x1..x4 uses adj5, adj4, adj3, adj1 (adj2 unused)
    const int*   a_rows[4] = { (const int*)d_in[13], (const int*)d_in[10], (const int*)d_in[7], (const int*)d_in[1] };
    const int*   a_cols[4] = { (const int*)d_in[14], (const int*)d_in[11], (const int*)d_in[8], (const int*)d_in[2] };
    const float* a_vals[4] = { (const float*)d_in[15], (const float*)d_in[12], (const float*)d_in[9], (const float*)d_in[3] };
    const float* W1 = (const float*)d_in[16]; const float* b1 = (const float*)d_in[17];
    const float* W2 = (const float*)d_in[18]; const float* b2 = (const float*)d_in[19];
    const float* W3 = (const float*)d_in[20]; const float* b3 = (const float*)d_in[21];
    const float* Wd = (const float*)d_in[22]; const float* bd = (const float*)d_in[23];
    float* out = (float*)d_out;

    size_t off = 0;
    auto alloc = [&](size_t bytes) {
        void* p = (char*)d_ws + off;
        off += (bytes + 255) & ~(size_t)255;
        return p;
    };
    float* xw1  = (float*)alloc((size_t)N * 256 * 4);
    float* bufA = (float*)alloc((size_t)N * 256 * 4);
    float* bufB = (float*)alloc((size_t)N * 256 * 4);
    int*   ptr  = (int*)alloc((size_t)(N + 1) * 4);
    int*   cnt  = (int*)alloc((size_t)N * 4);
    int*   fill = (int*)alloc((size_t)N * 4);
    int*   bsum = (int*)alloc(512);
    int*   scols = (int*)alloc((size_t)E * 4);
    float* svals = (float*)alloc((size_t)E * 4);

    const int NB = (N + 1023) / 1024;          // 98 scan blocks

    // shared across branches: xw1 = x @ W1
    k_gemm<512, 256><<<(N + 63) / 64, 256, 0, stream>>>(x, W1, xw1);

    for (int br = 0; br < 4; ++br) {
        const int* rows = a_rows[br];
        const int* cols = a_cols[br];
        const float* vals = a_vals[br];

        // CSR build (ws is re-poisoned each call: zero counters ourselves)
        k_zero2<<<(N + 255) / 256, 256, 0, stream>>>(cnt, fill, N);
        k_hist<<<E / 256, 256, 0, stream>>>(rows, cnt);
        k_blocksum<<<NB, 256, 0, stream>>>(cnt, bsum, N);
        k_scan_small<<<1, 128, 0, stream>>>(bsum, NB);
        k_scan_block<<<NB, 256, 0, stream>>>(cnt, bsum, ptr, N, E);
        k_scatter<<<E / 256, 256, 0, stream>>>(rows, cols, vals, ptr, fill, scols, svals);

        // layer 1: relu(A @ xw1 + b1)
        k_spmm<256><<<N / 4, 256, 0, stream>>>(ptr, scols, svals, xw1, b1, bufA);
        // layer 2: relu(A @ (h1 @ W2) + b2)
        k_gemm<256, 256><<<(N + 63) / 64, 256, 0, stream>>>(bufA, W2, bufB);
        k_spmm<256><<<N / 4, 256, 0, stream>>>(ptr, scols, svals, bufB, b2, bufA);
        // layer 3: relu(A @ (h2 @ W3) + b3)   (relu fused: consumer is relu(h3))
        k_gemm<256, 128><<<(N + 63) / 64, 256, 0, stream>>>(bufA, W3, bufB);
        k_spmm<128><<<N / 4, 256, 0, stream>>>(ptr, scols, svals, bufB, b3, bufA);
        // dense head -> out slice
        k_gemm4<<<N / 16, 256, 0, stream>>>(bufA, Wd, bd, out + (size_t)br * N * 16);
    }
}

// Round 2
// 7595.705 us; speedup vs baseline: 1.6630x; 1.6630x over previous
//
#include <hip/hip_runtime.h>

#define N_NODES 100000
#define N_EDGES 3200000

struct alignas(16) F4 { float v[4]; };
struct alignas(8)  F2 { float v[2]; };

// ---------------- utility ----------------
__global__ __launch_bounds__(256) void k_zero2(int* __restrict__ a, int* __restrict__ b, int n) {
    int i = blockIdx.x * 256 + threadIdx.x;
    if (i < n) { a[i] = 0; b[i] = 0; }
}

// ---------------- CSR build ----------------
__global__ __launch_bounds__(256) void k_hist(const int* __restrict__ rows, int* __restrict__ cnt) {
    int e = blockIdx.x * 256 + threadIdx.x;   // grid is exactly E/256
    atomicAdd(&cnt[rows[e]], 1);
}

__global__ __launch_bounds__(256) void k_blocksum(const int* __restrict__ cnt, int* __restrict__ bsum, int n) {
    __shared__ int red[256];
    int b = blockIdx.x, t = threadIdx.x;
    int base = b * 1024 + t * 4;
    int s = 0;
#pragma unroll
    for (int j = 0; j < 4; ++j) { int idx = base + j; if (idx < n) s += cnt[idx]; }
    red[t] = s; __syncthreads();
    for (int off = 128; off > 0; off >>= 1) {
        if (t < off) red[t] += red[t + off];
        __syncthreads();
    }
    if (t == 0) bsum[b] = red[0];
}

__global__ __launch_bounds__(128) void k_scan_small(int* __restrict__ b, int n) {
    __shared__ int s[128];
    int t = threadIdx.x;
    int v = (t < n) ? b[t] : 0;
    s[t] = v; __syncthreads();
    for (int off = 1; off < 128; off <<= 1) {
        int x = (t >= off) ? s[t - off] : 0;
        __syncthreads();
        s[t] += x;
        __syncthreads();
    }
    if (t < n) b[t] = s[t] - v;
}

__global__ __launch_bounds__(256) void k_scan_block(const int* __restrict__ cnt, const int* __restrict__ bsum,
                                                    int* __restrict__ ptr, int n, int total) {
    __shared__ int ts[256];
    int b = blockIdx.x, t = threadIdx.x;
    int base = b * 1024 + t * 4;
    int v[4]; int s = 0;
#pragma unroll
    for (int j = 0; j < 4; ++j) { v[j] = (base + j < n) ? cnt[base + j] : 0; s += v[j]; }
    ts[t] = s; __syncthreads();
    for (int off = 1; off < 256; off <<= 1) {
        int x = (t >= off) ? ts[t - off] : 0;
        __syncthreads();
        ts[t] += x;
        __syncthreads();
    }
    int run = bsum[b] + ts[t] - s;
#pragma unroll
    for (int j = 0; j < 4; ++j) { if (base + j < n) ptr[base + j] = run; run += v[j]; }
    if (b == 0 && t == 0) ptr[n] = total;
}

__global__ __launch_bounds__(256) void k_scatter(const int* __restrict__ rows, const int* __restrict__ cols,
                                                  const float* __restrict__ vals, const int* __restrict__ ptr,
                                                  int* __restrict__ fill, int* __restrict__ scols,
                                                  float* __restrict__ svals) {
    int e = blockIdx.x * 256 + threadIdx.x;
    int r = rows[e];
    int p = ptr[r] + atomicAdd(&fill[r], 1);
    scols[p] = cols[e];
    svals[p] = vals[e];
}

// ---------------- SpMM (CSR, wave per row, fused bias+ReLU) ----------------
template<int D>
__global__ __launch_bounds__(256) void k_spmm(const int* __restrict__ ptr, const int* __restrict__ scols,
                                              const float* __restrict__ svals, const float* __restrict__ dense,
                                              const float* __restrict__ bias, float* __restrict__ outp) {
    constexpr int V = D / 64;
    int lane = threadIdx.x & 63;
    int row  = blockIdx.x * 4 + (threadIdx.x >> 6);
    float acc[V];
#pragma unroll
    for (int j = 0; j < V; ++j) acc[j] = 0.f;
    int s = ptr[row], e = ptr[row + 1];
    const float* __restrict__ dbase = dense + lane * V;
    int i = s;
    for (; i + 2 <= e; i += 2) {
        int   c0 = scols[i],  c1 = scols[i + 1];
        float v0 = svals[i],  v1 = svals[i + 1];
        const float* p0 = dbase + (size_t)c0 * D;
        const float* p1 = dbase + (size_t)c1 * D;
        if constexpr (V == 4) {
            F4 a0 = *(const F4*)p0, a1 = *(const F4*)p1;
#pragma unroll
            for (int j = 0; j < 4; ++j) acc[j] += v0 * a0.v[j] + v1 * a1.v[j];
        } else {
            F2 a0 = *(const F2*)p0, a1 = *(const F2*)p1;
#pragma unroll
            for (int j = 0; j < 2; ++j) acc[j] += v0 * a0.v[j] + v1 * a1.v[j];
        }
    }
    if (i < e) {
        int c0 = scols[i]; float v0 = svals[i];
        const float* p0 = dbase + (size_t)c0 * D;
        if constexpr (V == 4) {
            F4 a0 = *(const F4*)p0;
#pragma unroll
            for (int j = 0; j < 4; ++j) acc[j] += v0 * a0.v[j];
        } else {
            F2 a0 = *(const F2*)p0;
#pragma unroll
            for (int j = 0; j < 2; ++j) acc[j] += v0 * a0.v[j];
        }
    }
    const float* bp = bias + lane * V;
    float* op = outp + (size_t)row * D + lane * V;
    if constexpr (V == 4) {
        F4 o;
#pragma unroll
        for (int j = 0; j < 4; ++j) { float t = acc[j] + bp[j]; o.v[j] = t > 0.f ? t : 0.f; }
        *(F4*)op = o;
    } else {
        F2 o;
#pragma unroll
        for (int j = 0; j < 2; ++j) { float t = acc[j] + bp[j]; o.v[j] = t > 0.f ? t : 0.f; }
        *(F2*)op = o;
    }
}

// ---------------- fp32 GEMM: [N,K] @ [K,M] -> [N,M] ----------------
// BM=128 x BN=128 x BK=16, 256 threads, 8x8 micro-tile.
// Xs staged k-major (transposed) so fragment reads are b128 broadcasts;
// launch_bounds(256,3) caps VGPR ~170 -> no spill (acc=64 + frags + addr ~ 110).
template<int K, int M>
__global__ __launch_bounds__(256, 3) void k_gemm(const float* __restrict__ X, const float* __restrict__ W,
                                                 float* __restrict__ Y) {
    __shared__ float Xs[16][132];   // [k][row], pad 128->132
    __shared__ float Ws[16][132];   // [k][col]
    int tid = threadIdx.x;
    int tx = tid & 15, ty = tid >> 4;
    int r0 = blockIdx.x * 128;
    int c0 = blockIdx.y * 128;      // gridDim.y = M/128

    float acc[8][8];
#pragma unroll
    for (int i = 0; i < 8; ++i)
#pragma unroll
        for (int j = 0; j < 8; ++j) acc[i][j] = 0.f;

    for (int k0 = 0; k0 < K; k0 += 16) {
        __syncthreads();
        // stage X tile: 128 rows x 16 k, transposed into Xs[k][row]
#pragma unroll
        for (int i = 0; i < 2; ++i) {
            int f  = tid + i * 256;
            int rr = f >> 2;            // 0..127
            int kk = (f & 3) * 4;       // 0,4,8,12
            int grow = r0 + rr;
            F4 v = {0.f, 0.f, 0.f, 0.f};
            if (grow < N_NODES) v = *(const F4*)&X[(size_t)grow * K + k0 + kk];
            Xs[kk + 0][rr] = v.v[0];
            Xs[kk + 1][rr] = v.v[1];
            Xs[kk + 2][rr] = v.v[2];
            Xs[kk + 3][rr] = v.v[3];
        }
        // stage W tile: 16 k x 128 cols, natural layout (coalesced)
#pragma unroll
        for (int i = 0; i < 2; ++i) {
            int f  = tid + i * 256;
            int kk = f >> 5;            // 0..15
            int cc = (f & 31) * 4;      // 0..124
            *(F4*)&Ws[kk][cc] = *(const F4*)&W[(size_t)(k0 + kk) * M + c0 + cc];
        }
        __syncthreads();
#pragma unroll 4
        for (int kk = 0; kk < 16; ++kk) {
            F4 a0 = *(const F4*)&Xs[kk][ty * 8];
            F4 a1 = *(const F4*)&Xs[kk][ty * 8 + 4];
            F4 b0 = *(const F4*)&Ws[kk][tx * 8];
            F4 b1 = *(const F4*)&Ws[kk][tx * 8 + 4];
#pragma unroll
            for (int i = 0; i < 4; ++i)
#pragma unroll
                for (int j = 0; j < 4; ++j) {
                    acc[i][j]         += a0.v[i] * b0.v[j];
                    acc[i][j + 4]     += a0.v[i] * b1.v[j];
                    acc[i + 4][j]     += a1.v[i] * b0.v[j];
                    acc[i + 4][j + 4] += a1.v[i] * b1.v[j];
                }
        }
    }
    // epilogue: 8 rows x 8 cols per thread
#pragma unroll
    for (int i = 0; i < 8; ++i) {
        int grow = r0 + ty * 8 + i;
        if (grow < N_NODES) {
            F4 o0, o1;
#pragma unroll
            for (int j = 0; j < 4; ++j) { o0.v[j] = acc[i][j]; o1.v[j] = acc[i][j + 4]; }
            float* yp = &Y[(size_t)grow * M + c0 + tx * 8];
            *(F4*)yp = o0;
            *(F4*)(yp + 4) = o1;
        }
    }
}

// ---------------- final dense: [N,128] @ [128,16] + bd ----------------
__global__ __launch_bounds__(256) void k_gemm4(const float* __restrict__ X, const float* __restrict__ Wd,
                                               const float* __restrict__ bd, float* __restrict__ out) {
    __shared__ float xs[16][132];
    __shared__ float ws[128 * 16];
    __shared__ float bs[16];
    int tid = threadIdx.x;
    int r0 = blockIdx.x * 16;
#pragma unroll
    for (int i = 0; i < 2; ++i) {
        int f = tid + i * 256;
        *(F4*)&ws[f * 4] = *(const F4*)&Wd[f * 4];
    }
    if (tid < 16) bs[tid] = bd[tid];
#pragma unroll
    for (int i = 0; i < 2; ++i) {
        int f  = tid + i * 256;
        int rr = f >> 5;
        int c4 = f & 31;
        *(F4*)&xs[rr][c4 * 4] = *(const F4*)&X[(size_t)(r0 + rr) * 128 + c4 * 4];
    }
    __syncthreads();
    int c = tid & 15, r = tid >> 4;
    float acc = bs[c];
#pragma unroll
    for (int k = 0; k < 128; ++k) acc += xs[r][k] * ws[k * 16 + c];
    out[(size_t)(r0 + r) * 16 + c] = acc;
}

// ---------------- host ----------------
extern "C" void kernel_launch(void* const* d_in, const int* in_sizes, int n_in,
                              void* d_out, int out_size, void* d_ws, size_t ws_size,
                              hipStream_t stream) {
    const int N = N_NODES, E = N_EDGES;
    const float* x  = (const float*)d_in[0];
    // branch order x1..x4 uses adj5, adj4, adj3, adj1 (adj2 unused)
    const int*   a_rows[4] = { (const int*)d_in[13], (const int*)d_in[10], (const int*)d_in[7], (const int*)d_in[1] };
    const int*   a_cols[4] = { (const int*)d_in[14], (const int*)d_in[11], (const int*)d_in[8], (const int*)d_in[2] };
    const float* a_vals[4] = { (const float*)d_in[15], (const float*)d_in[12], (const float*)d_in[9], (const float*)d_in[3] };
    const float* W1 = (const float*)d_in[16]; const float* b1 = (const float*)d_in[17];
    const float* W2 = (const float*)d_in[18]; const float* b2 = (const float*)d_in[19];
    const float* W3 = (const float*)d_in[20]; const float* b3 = (const float*)d_in[21];
    const float* Wd = (const float*)d_in[22]; const float* bd = (const float*)d_in[23];
    float* out = (float*)d_out;

    size_t off = 0;
    auto alloc = [&](size_t bytes) {
        void* p = (char*)d_ws + off;
        off += (bytes + 255) & ~(size_t)255;
        return p;
    };
    float* xw1  = (float*)alloc((size_t)N * 256 * 4);
    float* bufA = (float*)alloc((size_t)N * 256 * 4);
    float* bufB = (float*)alloc((size_t)N * 256 * 4);
    int*   ptr  = (int*)alloc((size_t)(N + 1) * 4);
    int*   cnt  = (int*)alloc((size_t)N * 4);
    int*   fill = (int*)alloc((size_t)N * 4);
    int*   bsum = (int*)alloc(512);
    int*   scols = (int*)alloc((size_t)E * 4);
    float* svals = (float*)alloc((size_t)E * 4);

    const int NB = (N + 1023) / 1024;

    const int GR = (N + 127) / 128;   // 782 row tiles

    // shared across branches: xw1 = x @ W1
    {
        dim3 g(GR, 2);
        k_gemm<512, 256><<<g, 256, 0, stream>>>(x, W1, xw1);
    }

    for (int br = 0; br < 4; ++br) {
        const int* rows = a_rows[br];
        const int* cols = a_cols[br];
        const float* vals = a_vals[br];

        // CSR build (ws is re-poisoned each call: zero counters ourselves)
        k_zero2<<<(N + 255) / 256, 256, 0, stream>>>(cnt, fill, N);
        k_hist<<<E / 256, 256, 0, stream>>>(rows, cnt);
        k_blocksum<<<NB, 256, 0, stream>>>(cnt, bsum, N);
        k_scan_small<<<1, 128, 0, stream>>>(bsum, NB);
        k_scan_block<<<NB, 256, 0, stream>>>(cnt, bsum, ptr, N, E);
        k_scatter<<<E / 256, 256, 0, stream>>>(rows, cols, vals, ptr, fill, scols, svals);

        // layer 1: relu(A @ xw1 + b1)
        k_spmm<256><<<N / 4, 256, 0, stream>>>(ptr, scols, svals, xw1, b1, bufA);
        // layer 2: relu(A @ (h1 @ W2) + b2)
        {
            dim3 g(GR, 2);
            k_gemm<256, 256><<<g, 256, 0, stream>>>(bufA, W2, bufB);
        }
        k_spmm<256><<<N / 4, 256, 0, stream>>>(ptr, scols, svals, bufB, b2, bufA);
        // layer 3: relu(A @ (h2 @ W3) + b3)   (relu fused: consumer is relu(h3))
        {
            dim3 g(GR, 1);
            k_gemm<256, 128><<<g, 256, 0, stream>>>(bufA, W3, bufB);
        }
        k_spmm<128><<<N / 4, 256, 0, stream>>>(ptr, scols, svals, bufB, b3, bufA);
        // dense head -> out slice
        k_gemm4<<<N / 16, 256, 0, stream>>>(bufA, Wd, bd, out + (size_t)br * N * 16);
    }
}

// Round 3
// 4737.384 us; speedup vs baseline: 2.6663x; 1.6034x over previous
//
#include <hip/hip_runtime.h>

#define N_NODES 100000
#define N_EDGES 3200000

struct alignas(16) F4 { float v[4]; };

typedef _Float16 half8v __attribute__((ext_vector_type(8)));
typedef _Float16 half4v __attribute__((ext_vector_type(4)));
typedef _Float16 half2v __attribute__((ext_vector_type(2)));
typedef float    f4v    __attribute__((ext_vector_type(4)));

// ---------------- utility ----------------
__global__ __launch_bounds__(256) void k_zero2(int* __restrict__ a, int* __restrict__ b, int n) {
    int i = blockIdx.x * 256 + threadIdx.x;
    if (i < n) { a[i] = 0; b[i] = 0; }
}

__global__ __launch_bounds__(256) void k_f2h(const float* __restrict__ in, _Float16* __restrict__ out, int n4) {
    int i = blockIdx.x * 256 + threadIdx.x;
    if (i < n4) {
        F4 v = *(const F4*)(in + (size_t)i * 4);
        half4v h;
#pragma unroll
        for (int j = 0; j < 4; ++j) h[j] = (_Float16)v.v[j];
        *(half4v*)(out + (size_t)i * 4) = h;
    }
}

// W [K][M] fp32 -> Wt [M][K] fp16 (tiny weights, perf-irrelevant)
__global__ __launch_bounds__(256) void k_wt(const float* __restrict__ W, _Float16* __restrict__ Wt, int K, int M) {
    int i = blockIdx.x * 256 + threadIdx.x;
    if (i < K * M) {
        int k = i / M, m = i - k * M;
        Wt[(size_t)m * K + k] = (_Float16)W[i];
    }
}

// ---------------- CSR build ----------------
__global__ __launch_bounds__(256) void k_hist(const int* __restrict__ rows, int* __restrict__ cnt) {
    int e = blockIdx.x * 256 + threadIdx.x;   // grid is exactly E/256
    atomicAdd(&cnt[rows[e]], 1);
}

__global__ __launch_bounds__(256) void k_blocksum(const int* __restrict__ cnt, int* __restrict__ bsum, int n) {
    __shared__ int red[256];
    int b = blockIdx.x, t = threadIdx.x;
    int base = b * 1024 + t * 4;
    int s = 0;
#pragma unroll
    for (int j = 0; j < 4; ++j) { int idx = base + j; if (idx < n) s += cnt[idx]; }
    red[t] = s; __syncthreads();
    for (int off = 128; off > 0; off >>= 1) {
        if (t < off) red[t] += red[t + off];
        __syncthreads();
    }
    if (t == 0) bsum[b] = red[0];
}

__global__ __launch_bounds__(128) void k_scan_small(int* __restrict__ b, int n) {
    __shared__ int s[128];
    int t = threadIdx.x;
    int v = (t < n) ? b[t] : 0;
    s[t] = v; __syncthreads();
    for (int off = 1; off < 128; off <<= 1) {
        int x = (t >= off) ? s[t - off] : 0;
        __syncthreads();
        s[t] += x;
        __syncthreads();
    }
    if (t < n) b[t] = s[t] - v;
}

__global__ __launch_bounds__(256) void k_scan_block(const int* __restrict__ cnt, const int* __restrict__ bsum,
                                                    int* __restrict__ ptr, int n, int total) {
    __shared__ int ts[256];
    int b = blockIdx.x, t = threadIdx.x;
    int base = b * 1024 + t * 4;
    int v[4]; int s = 0;
#pragma unroll
    for (int j = 0; j < 4; ++j) { v[j] = (base + j < n) ? cnt[base + j] : 0; s += v[j]; }
    ts[t] = s; __syncthreads();
    for (int off = 1; off < 256; off <<= 1) {
        int x = (t >= off) ? ts[t - off] : 0;
        __syncthreads();
        ts[t] += x;
        __syncthreads();
    }
    int run = bsum[b] + ts[t] - s;
#pragma unroll
    for (int j = 0; j < 4; ++j) { if (base + j < n) ptr[base + j] = run; run += v[j]; }
    if (b == 0 && t == 0) ptr[n] = total;
}

__global__ __launch_bounds__(256) void k_scatter(const int* __restrict__ rows, const int* __restrict__ cols,
                                                  const float* __restrict__ vals, const int* __restrict__ ptr,
                                                  int* __restrict__ fill, int* __restrict__ scols,
                                                  float* __restrict__ svals) {
    int e = blockIdx.x * 256 + threadIdx.x;
    int r = rows[e];
    int p = ptr[r] + atomicAdd(&fill[r], 1);
    scols[p] = cols[e];
    svals[p] = vals[e];
}

// ---------------- SpMM (CSR, wave per row, fp16 gather, fp32 acc, fused bias+ReLU, fp16 out) ----------------
template<int D>
__global__ __launch_bounds__(256) void k_spmm(const int* __restrict__ ptr, const int* __restrict__ scols,
                                              const float* __restrict__ svals, const _Float16* __restrict__ dense,
                                              const float* __restrict__ bias, _Float16* __restrict__ outp) {
    constexpr int V = D / 64;                    // halfs per lane (4 for D=256, 2 for D=128)
    int lane = threadIdx.x & 63;
    int row  = blockIdx.x * 4 + (threadIdx.x >> 6);   // grid*4 == N exactly
    float acc[V];
#pragma unroll
    for (int j = 0; j < V; ++j) acc[j] = 0.f;
    int s = ptr[row], e = ptr[row + 1];
    const _Float16* __restrict__ dbase = dense + lane * V;
    int i = s;
    // 4 independent gather chains per iteration
    for (; i + 4 <= e; i += 4) {
        int c0 = scols[i], c1 = scols[i + 1], c2 = scols[i + 2], c3 = scols[i + 3];
        float v0 = svals[i], v1 = svals[i + 1], v2 = svals[i + 2], v3 = svals[i + 3];
        if constexpr (V == 4) {
            half4v a0 = *(const half4v*)(dbase + (size_t)c0 * D);
            half4v a1 = *(const half4v*)(dbase + (size_t)c1 * D);
            half4v a2 = *(const half4v*)(dbase + (size_t)c2 * D);
            half4v a3 = *(const half4v*)(dbase + (size_t)c3 * D);
#pragma unroll
            for (int j = 0; j < 4; ++j)
                acc[j] += v0 * (float)a0[j] + v1 * (float)a1[j] + v2 * (float)a2[j] + v3 * (float)a3[j];
        } else {
            half2v a0 = *(const half2v*)(dbase + (size_t)c0 * D);
            half2v a1 = *(const half2v*)(dbase + (size_t)c1 * D);
            half2v a2 = *(const half2v*)(dbase + (size_t)c2 * D);
            half2v a3 = *(const half2v*)(dbase + (size_t)c3 * D);
#pragma unroll
            for (int j = 0; j < 2; ++j)
                acc[j] += v0 * (float)a0[j] + v1 * (float)a1[j] + v2 * (float)a2[j] + v3 * (float)a3[j];
        }
    }
    for (; i < e; ++i) {
        int c0 = scols[i]; float v0 = svals[i];
        if constexpr (V == 4) {
            half4v a0 = *(const half4v*)(dbase + (size_t)c0 * D);
#pragma unroll
            for (int j = 0; j < 4; ++j) acc[j] += v0 * (float)a0[j];
        } else {
            half2v a0 = *(const half2v*)(dbase + (size_t)c0 * D);
#pragma unroll
            for (int j = 0; j < 2; ++j) acc[j] += v0 * (float)a0[j];
        }
    }
    // epilogue: +bias (fp32), ReLU, round to fp16
    const float* bp = bias + lane * V;
    _Float16* op = outp + (size_t)row * D + lane * V;
    if constexpr (V == 4) {
        half4v o;
#pragma unroll
        for (int j = 0; j < 4; ++j) { float t = acc[j] + bp[j]; o[j] = (_Float16)(t > 0.f ? t : 0.f); }
        *(half4v*)op = o;
    } else {
        half2v o;
#pragma unroll
        for (int j = 0; j < 2; ++j) { float t = acc[j] + bp[j]; o[j] = (_Float16)(t > 0.f ? t : 0.f); }
        *(half2v*)op = o;
    }
}

// ---------------- MFMA fp16 GEMM: A[N][K]h @ W[K][M] -> Y[N][M]h ----------------
// No LDS: A-frags from global (L3-cached), B-frags from pre-transposed Wt[M][K] (L2-resident).
// Block 256 thr = 4 waves; wave owns 32 rows x 128 cols (2 m-tiles x 8 n-tiles of 16x16).
// mfma_f32_16x16x32_f16: A row=lane&15, kgroup=(lane>>4)*8 (8 contig halfs); B symmetric;
// C/D: col=lane&15, row=(lane>>4)*4+reg (guide-verified, dtype-independent).
template<int K, int M>
__global__ __launch_bounds__(256, 3) void k_gemm_mfma(const _Float16* __restrict__ A,
                                                      const _Float16* __restrict__ Bt,
                                                      _Float16* __restrict__ Y) {
    int tid = threadIdx.x;
    int lane = tid & 63, w = tid >> 6;
    int r0 = blockIdx.x * 128 + w * 32;
    int c0 = blockIdx.y * 128;
    int kg = (lane >> 4) * 8;
    int lm = lane & 15;

    const _Float16* ap[2];
#pragma unroll
    for (int mt = 0; mt < 2; ++mt) {
        int r = r0 + mt * 16 + lm;
        if (r > N_NODES - 1) r = N_NODES - 1;     // clamp; store is masked below
        ap[mt] = A + (size_t)r * K + kg;
    }
    const _Float16* bp[8];
#pragma unroll
    for (int nt = 0; nt < 8; ++nt)
        bp[nt] = Bt + (size_t)(c0 + nt * 16 + lm) * K + kg;

    f4v acc[2][8];
#pragma unroll
    for (int mt = 0; mt < 2; ++mt)
#pragma unroll
        for (int nt = 0; nt < 8; ++nt) acc[mt][nt] = (f4v){0.f, 0.f, 0.f, 0.f};

#pragma unroll 2
    for (int k0 = 0; k0 < K; k0 += 32) {
        half8v a0 = *(const half8v*)(ap[0] + k0);
        half8v a1 = *(const half8v*)(ap[1] + k0);
#pragma unroll
        for (int nt = 0; nt < 8; ++nt) {
            half8v b = *(const half8v*)(bp[nt] + k0);
            acc[0][nt] = __builtin_amdgcn_mfma_f32_16x16x32_f16(a0, b, acc[0][nt], 0, 0, 0);
            acc[1][nt] = __builtin_amdgcn_mfma_f32_16x16x32_f16(a1, b, acc[1][nt], 0, 0, 0);
        }
    }

    int rbase = (lane >> 4) * 4;
#pragma unroll
    for (int mt = 0; mt < 2; ++mt)
#pragma unroll
        for (int reg = 0; reg < 4; ++reg) {
            int row = r0 + mt * 16 + rbase + reg;
            if (row < N_NODES) {
                _Float16* yp = Y + (size_t)row * M + c0 + lm;
#pragma unroll
                for (int nt = 0; nt < 8; ++nt)
                    yp[nt * 16] = (_Float16)acc[mt][nt][reg];
            }
        }
}

// ---------------- final dense: [N,128]h @ Wd[128,16]f + bd -> fp32 out ----------------
__global__ __launch_bounds__(256) void k_gemm4(const _Float16* __restrict__ X, const float* __restrict__ Wd,
                                               const float* __restrict__ bd, float* __restrict__ out) {
    __shared__ float xs[16][132];      // pad 128 -> 132
    __shared__ float ws[128 * 16];
    __shared__ float bs[16];
    int tid = threadIdx.x;
    int r0 = blockIdx.x * 16;          // N % 16 == 0
#pragma unroll
    for (int i = 0; i < 2; ++i) {      // stage Wd: 2048 floats
        int f = tid + i * 256;
        *(F4*)&ws[f * 4] = *(const F4*)&Wd[f * 4];
    }
    if (tid < 16) bs[tid] = bd[tid];
    {
        int rr = tid >> 4;             // 0..15
        int c8 = (tid & 15) * 8;       // 0..120
        half8v v = *(const half8v*)&X[(size_t)(r0 + rr) * 128 + c8];
#pragma unroll
        for (int j = 0; j < 8; ++j) xs[rr][c8 + j] = (float)v[j];
    }
    __syncthreads();
    int c = tid & 15, r = tid >> 4;
    float acc = bs[c];
#pragma unroll
    for (int k = 0; k < 128; ++k) acc += xs[r][k] * ws[k * 16 + c];
    out[(size_t)(r0 + r) * 16 + c] = acc;
}

// ---------------- host ----------------
extern "C" void kernel_launch(void* const* d_in, const int* in_sizes, int n_in,
                              void* d_out, int out_size, void* d_ws, size_t ws_size,
                              hipStream_t stream) {
    const int N = N_NODES, E = N_EDGES;
    const float* x  = (const float*)d_in[0];
    // branch order x1..x4 uses adj5, adj4, adj3, adj1 (adj2 unused)
    const int*   a_rows[4] = { (const int*)d_in[13], (const int*)d_in[10], (const int*)d_in[7], (const int*)d_in[1] };
    const int*   a_cols[4] = { (const int*)d_in[14], (const int*)d_in[11], (const int*)d_in[8], (const int*)d_in[2] };
    const float* a_vals[4] = { (const float*)d_in[15], (const float*)d_in[12], (const float*)d_in[9], (const float*)d_in[3] };
    const float* W1 = (const float*)d_in[16]; const float* b1 = (const float*)d_in[17];
    const float* W2 = (const float*)d_in[18]; const float* b2 = (const float*)d_in[19];
    const float* W3 = (const float*)d_in[20]; const float* b3 = (const float*)d_in[21];
    const float* Wd = (const float*)d_in[22]; const float* bd = (const float*)d_in[23];
    float* out = (float*)d_out;

    size_t off = 0;
    auto alloc = [&](size_t bytes) {
        void* p = (char*)d_ws + off;
        off += (bytes + 255) & ~(size_t)255;
        return p;
    };
    _Float16* xh    = (_Float16*)alloc((size_t)N * 512 * 2);
    _Float16* xw1h  = (_Float16*)alloc((size_t)N * 256 * 2);
    _Float16* bufA  = (_Float16*)alloc((size_t)N * 256 * 2);
    _Float16* bufB  = (_Float16*)alloc((size_t)N * 256 * 2);
    _Float16* W1t   = (_Float16*)alloc((size_t)256 * 512 * 2);
    _Float16* W2t   = (_Float16*)alloc((size_t)256 * 256 * 2);
    _Float16* W3t   = (_Float16*)alloc((size_t)128 * 256 * 2);
    int*   ptr  = (int*)alloc((size_t)(N + 1) * 4);
    int*   cnt  = (int*)alloc((size_t)N * 4);
    int*   fill = (int*)alloc((size_t)N * 4);
    int*   bsum = (int*)alloc(512);
    int*   scols = (int*)alloc((size_t)E * 4);
    float* svals = (float*)alloc((size_t)E * 4);

    const int NB = (N + 1023) / 1024;   // 98 scan blocks
    const int GR = (N + 127) / 128;     // 782 row tiles

    // fp16 conversions (every call; ws is re-poisoned)
    k_f2h<<<(N * 512 / 4 + 255) / 256, 256, 0, stream>>>(x, xh, N * 512 / 4);
    k_wt<<<(512 * 256 + 255) / 256, 256, 0, stream>>>(W1, W1t, 512, 256);
    k_wt<<<(256 * 256 + 255) / 256, 256, 0, stream>>>(W2, W2t, 256, 256);
    k_wt<<<(256 * 128 + 255) / 256, 256, 0, stream>>>(W3, W3t, 256, 128);

    // shared across branches: xw1 = x @ W1
    {
        dim3 g(GR, 2);
        k_gemm_mfma<512, 256><<<g, 256, 0, stream>>>(xh, W1t, xw1h);
    }

    for (int br = 0; br < 4; ++br) {
        const int* rows = a_rows[br];
        const int* cols = a_cols[br];
        const float* vals = a_vals[br];

        // CSR build
        k_zero2<<<(N + 255) / 256, 256, 0, stream>>>(cnt, fill, N);
        k_hist<<<E / 256, 256, 0, stream>>>(rows, cnt);
        k_blocksum<<<NB, 256, 0, stream>>>(cnt, bsum, N);
        k_scan_small<<<1, 128, 0, stream>>>(bsum, NB);
        k_scan_block<<<NB, 256, 0, stream>>>(cnt, bsum, ptr, N, E);
        k_scatter<<<E / 256, 256, 0, stream>>>(rows, cols, vals, ptr, fill, scols, svals);

        // layer 1: relu(A @ xw1 + b1)
        k_spmm<256><<<N / 4, 256, 0, stream>>>(ptr, scols, svals, xw1h, b1, bufA);
        // layer 2: relu(A @ (h1 @ W2) + b2)
        {
            dim3 g(GR, 2);
            k_gemm_mfma<256, 256><<<g, 256, 0, stream>>>(bufA, W2t, bufB);
        }
        k_spmm<256><<<N / 4, 256, 0, stream>>>(ptr, scols, svals, bufB, b2, bufA);
        // layer 3: relu fused into spmm (consumer is relu(h3))
        {
            dim3 g(GR, 1);
            k_gemm_mfma<256, 128><<<g, 256, 0, stream>>>(bufA, W3t, bufB);
        }
        k_spmm<128><<<N / 4, 256, 0, stream>>>(ptr, scols, svals, bufB, b3, bufA);
        // dense head -> out slice
        k_gemm4<<<N / 16, 256, 0, stream>>>(bufA, Wd, bd, out + (size_t)br * N * 16);
    }
}